// Round 1
// baseline (1043.671 us; speedup 1.0000x reference)
//
#include <hip/hip_runtime.h>

// Problem constants (fixed by the reference: B=16, D=256, K=64, H=W=96)
#define NDIM  256          // feature dim D
#define NK    64           // codewords K
#define NPIX  9216         // H*W
#define NB    16           // batch
#define TN    64           // pixels per tile (== wavefront size: lane <-> pixel)
#define NT    4            // tiles per block
#define CHUNKS 36          // NPIX / (TN*NT)

typedef _Float16 half2_t __attribute__((ext_vector_type(2)));

__device__ __forceinline__ float fdot2(half2_t a, half2_t b, float c) {
  // v_dot2_f32_f16: 2 f16 MACs into f32 accumulator
  return __builtin_amdgcn_fdot2(a, b, c, false);
}

// ---- c2[k] = sum_d C[k][d]^2  (once, tiny) ----
__global__ void c2_kernel(const float* __restrict__ Cw, float* __restrict__ c2) {
  __shared__ float tmp[256];
  const int t = threadIdx.x;
  const int k = t >> 2, q = t & 3;
  float s = 0.f;
  const float* row = Cw + k * NDIM + q * 64;
  for (int i = 0; i < 64; ++i) { float v = row[i]; s += v * v; }
  tmp[t] = s;
  __syncthreads();
  if (t < NK) c2[t] = tmp[4*t] + tmp[4*t+1] + tmp[4*t+2] + tmp[4*t+3];
}

// ---- fused: distances -> softmax -> residual aggregation ----
// block = 256 threads = 4 waves; grid = NB*CHUNKS = 576 blocks.
// Phase 1 (GEMM1): lane=pixel, wave=k-slab of 16; X loads coalesced along n,
//                  codeword loads wave-uniform (scalarize). fp32.
// Phase 2: softmax over K=64 (cross-wave via LDS).
// Phase 3 (agg):   thread=(k, d-interleave) with 64 fp32 accs held across
//                  NT tiles; f16 dot2 over pixels from LDS. One atomic pass.
__global__ __launch_bounds__(256, 2) void encode_main(
    const float* __restrict__ X, const float* __restrict__ Cw,
    const float* __restrict__ scale, const float* __restrict__ c2,
    float* __restrict__ E_ws, float* __restrict__ asum_ws)
{
  // row stride 72 f16 = 144 B: 16B-aligned rows; agg reads hit disjoint bank
  // quads (row stride 36 dwords, lanes 4 consecutive rows -> banks {0,4,8,12})
  __shared__ _Float16 Xtd[NDIM][72];   // transposed X tile, f16   (36.9 KB)
  __shared__ _Float16 Al[NK][72];      // softmax weights [k][pix] ( 9.2 KB)
  __shared__ float    red[4][TN];      // cross-wave softmax scratch (1 KB)

  const int tid  = threadIdx.x;
  const int w    = __builtin_amdgcn_readfirstlane(tid >> 6); // wave id 0..3
  const int lane = tid & 63;                                  // pixel in tile
  const int b      = blockIdx.x / CHUNKS;
  const int chunk  = blockIdx.x % CHUNKS;
  const int n_base = chunk * (TN * NT);
  const float* Xb  = X + (size_t)b * NDIM * NPIX;
  const int kbase  = w * 16;     // this wave's k-slab (wave-uniform)
  const int ka     = tid >> 2;   // aggregation: codeword 0..63
  const int dsl    = tid & 3;    // aggregation: d interleave 0..3

  float eacc[64];                // E partial [ka][d = 32c+4j+dsl]
#pragma unroll
  for (int i = 0; i < 64; ++i) eacc[i] = 0.f;
  float asum_acc = 0.f;          // sum_n A[n][k=tid] (threads 0..63)

  for (int t = 0; t < NT; ++t) {
    __syncthreads();             // prev tile's aggregation done before restage
    const int n0 = n_base + t * TN;

    // ---- phase 1: xc + x^2 + stage f16 transpose ----
    float acc[16];
#pragma unroll
    for (int i = 0; i < 16; ++i) acc[i] = 0.f;
    float xsq = 0.f;
#pragma unroll 2
    for (int dc = 0; dc < NDIM; dc += 4) {
      const float x0 = Xb[(size_t)(dc+0)*NPIX + n0 + lane];
      const float x1 = Xb[(size_t)(dc+1)*NPIX + n0 + lane];
      const float xx = Xb[(size_t)(dc+2)*NPIX + n0 + lane];
      const float x3 = Xb[(size_t)(dc+3)*NPIX + n0 + lane];
      xsq += x0*x0 + x1*x1 + xx*xx + x3*x3;
      if ((dc >> 6) == w) {      // each wave stages its d-quarter (uniform)
        Xtd[dc+0][lane] = (_Float16)x0;
        Xtd[dc+1][lane] = (_Float16)x1;
        Xtd[dc+2][lane] = (_Float16)xx;
        Xtd[dc+3][lane] = (_Float16)x3;
      }
#pragma unroll
      for (int kk = 0; kk < 16; ++kk) {   // wave-uniform codeword address
        const float4 c = *(const float4*)(Cw + (kbase + kk) * NDIM + dc);
        acc[kk] += x0*c.x + x1*c.y + xx*c.z + x3*c.w;
      }
    }

    // ---- phase 2: softmax over k (64 values live across the 4 waves) ----
    float sl[16];
    float m = -3.0e38f;
#pragma unroll
    for (int kk = 0; kk < 16; ++kk) {
      const float s = scale[kbase+kk] * (xsq - 2.f*acc[kk] + c2[kbase+kk]);
      sl[kk] = s; m = fmaxf(m, s);
    }
    red[w][lane] = m;
    __syncthreads();
    m = fmaxf(fmaxf(red[0][lane], red[1][lane]),
              fmaxf(red[2][lane], red[3][lane]));
    float psum = 0.f;
#pragma unroll
    for (int kk = 0; kk < 16; ++kk) {
      const float p = __expf(sl[kk] - m); sl[kk] = p; psum += p;
    }
    __syncthreads();             // all max-reads done before reuse
    red[w][lane] = psum;
    __syncthreads();
    const float tot  = red[0][lane] + red[1][lane] + red[2][lane] + red[3][lane];
    const float rinv = 1.f / tot;
#pragma unroll
    for (int kk = 0; kk < 16; ++kk)
      Al[kbase+kk][lane] = (_Float16)(sl[kk] * rinv);
    __syncthreads();             // Al + Xtd visible to aggregation

    // ---- phase 3: E[ka][d] += sum_l A[ka][l] * X[d][l]  (f16 dot2) ----
    for (int lc = 0; lc < 8; ++lc) {
      const int l0 = lc * 8;
      const half2_t* ap = (const half2_t*)&Al[ka][l0];
      const half2_t a0 = ap[0], a1 = ap[1], a2 = ap[2], a3 = ap[3];
#pragma unroll
      for (int c = 0; c < 8; ++c) {
#pragma unroll
        for (int j = 0; j < 8; ++j) {
          const int d = c*32 + j*4 + dsl;
          const half2_t* xp = (const half2_t*)&Xtd[d][l0];
          float e = eacc[c*8+j];
          e = fdot2(xp[0], a0, e);
          e = fdot2(xp[1], a1, e);
          e = fdot2(xp[2], a2, e);
          e = fdot2(xp[3], a3, e);
          eacc[c*8+j] = e;
        }
      }
      if (tid < NK) {            // asum for codeword row `tid`
        const half2_t* sp = (const half2_t*)&Al[tid][l0];
        const half2_t one = {(_Float16)1.f, (_Float16)1.f};
        asum_acc = fdot2(sp[0], one, asum_acc);
        asum_acc = fdot2(sp[1], one, asum_acc);
        asum_acc = fdot2(sp[2], one, asum_acc);
        asum_acc = fdot2(sp[3], one, asum_acc);
      }
    }
  }

  // ---- one atomic pass per block into L2-resident accumulator ----
  float* Ebk = E_ws + ((size_t)b * NK + ka) * NDIM;
#pragma unroll
  for (int c = 0; c < 8; ++c)
#pragma unroll
    for (int j = 0; j < 8; ++j)
      atomicAdd(&Ebk[c*32 + j*4 + dsl], eacc[c*8+j]);
  if (tid < NK) atomicAdd(&asum_ws[b*NK + tid], asum_acc);
}

// ---- E[b][k][d] = E_ws[b][k][d] - asum[b][k] * C[k][d] ----
__global__ void finalize_kernel(const float* __restrict__ E_ws,
                                const float* __restrict__ asum_ws,
                                const float* __restrict__ Cw,
                                float* __restrict__ out)
{
  const int i = blockIdx.x * 256 + threadIdx.x;
  const int d = i & (NDIM - 1);
  const int k = (i >> 8) & (NK - 1);
  const int b = i >> 14;
  out[i] = E_ws[i] - asum_ws[b*NK + k] * Cw[k*NDIM + d];
}

extern "C" void kernel_launch(void* const* d_in, const int* in_sizes, int n_in,
                              void* d_out, int out_size, void* d_ws, size_t ws_size,
                              hipStream_t stream) {
  const float* X     = (const float*)d_in[0];
  const float* Cw    = (const float*)d_in[1];
  const float* scale = (const float*)d_in[2];
  float* out = (float*)d_out;

  float* E_ws    = (float*)d_ws;                 // [NB][NK][NDIM] fp32, 1 MB
  float* asum_ws = E_ws + (size_t)NB*NK*NDIM;    // [NB][NK]
  float* c2      = asum_ws + NB*NK;              // [NK]

  // ws is re-poisoned before every call: re-zero the accumulators each launch
  hipMemsetAsync(d_ws, 0, (size_t)(NB*NK*NDIM + NB*NK) * sizeof(float), stream);
  c2_kernel<<<1, 256, 0, stream>>>(Cw, c2);
  encode_main<<<NB * CHUNKS, 256, 0, stream>>>(X, Cw, scale, c2, E_ws, asum_ws);
  finalize_kernel<<<(NB*NK*NDIM) / 256, 256, 0, stream>>>(E_ws, asum_ws, Cw, out);
}